// Round 1
// baseline (6037.473 us; speedup 1.0000x reference)
//
#include <hip/hip_runtime.h>
#include <stdint.h>
#include <math.h>

// plmDCA one Gibbs sweep — bitwise-faithful replay of the JAX reference.
// N=8192 sequences evolve independently -> one launch, per-block local state.
//
// RNG hypothesis: jax_threefry_partitionable = True (JAX >= 0.5 default).
// Sum-order hypothesis: Eigen MT contraction, k-blocks of KC=288, sequential
// within block, block partials added in order.  (Next candidates: 320, inf.)

#define NSEQ 8192
#define LRES 256
#define QST  21
#define KC   288              // Eigen gebp k-block (l1=32KB, AVX mr=24 nr=4)
#define SPB  32               // sequences per block
#define NTHREADS (SPB * QST)  // 672

__device__ __forceinline__ uint32_t rotl32(uint32_t v, uint32_t r) {
  return (v << r) | (v >> (32u - r));
}

// JAX/Random123 Threefry-2x32, 20 rounds.
__device__ __forceinline__ void threefry2x32(uint32_t k0, uint32_t k1,
                                             uint32_t c0, uint32_t c1,
                                             uint32_t& o0, uint32_t& o1) {
  uint32_t ks2 = k0 ^ k1 ^ 0x1BD11BDAu;
  uint32_t x0 = c0 + k0;
  uint32_t x1 = c1 + k1;
#define TF_ROUND(r) { x0 += x1; x1 = rotl32(x1, r); x1 ^= x0; }
  TF_ROUND(13u) TF_ROUND(15u) TF_ROUND(26u) TF_ROUND(6u)
  x0 += k1;  x1 += ks2 + 1u;
  TF_ROUND(17u) TF_ROUND(29u) TF_ROUND(16u) TF_ROUND(24u)
  x0 += ks2; x1 += k0 + 2u;
  TF_ROUND(13u) TF_ROUND(15u) TF_ROUND(26u) TF_ROUND(6u)
  x0 += k0;  x1 += k1 + 3u;
  TF_ROUND(17u) TF_ROUND(29u) TF_ROUND(16u) TF_ROUND(24u)
  x0 += k1;  x1 += ks2 + 4u;
  TF_ROUND(13u) TF_ROUND(15u) TF_ROUND(26u) TF_ROUND(6u)
  x0 += ks2; x1 += k0 + 5u;
#undef TF_ROUND
  o0 = x0; o1 = x1;
}

// JAX gumbel: -log(-log(uniform(tiny, 1))) with f32-rounded logs.
// Each log computed in f64 then rounded -> matches a correctly-rounded f32 log.
__device__ __forceinline__ float gumbel_f32(uint32_t bits) {
  float f = __uint_as_float((bits >> 9) | 0x3f800000u) - 1.0f;  // [0, 1-2^-23]
  float u = fmaxf(1.17549435e-38f, f + 1.17549435e-38f);        // JAX minval=tiny
  float w = (float)log((double)u);   // inner log, rounded to f32
  float t = -w;
  float g = -(float)log((double)t);  // outer log, rounded to f32
  return g;
}

__global__ __launch_bounds__(NTHREADS)
void gibbs_sweep(const float* __restrict__ X, const int* __restrict__ order,
                 const float* __restrict__ h, const float* __restrict__ J,
                 const float* __restrict__ betaPtr, float* __restrict__ out) {
  __shared__ int   bst[LRES][SPB];   // current state per (residue, local seq)
  __shared__ float vals[QST][SPB];   // per-category gumbel+logit values

  const int nl  = threadIdx.x;       // 0..31  local sequence
  const int a   = threadIdx.y;       // 0..20  category
  const int tid = nl + SPB * a;      // 0..671
  const int n0  = blockIdx.x * SPB;
  const int n   = n0 + nl;           // global sequence id
  const float beta = betaPtr[0];

  // ---- init state from one-hot X (values exactly 0.0/1.0) ----
  for (int idx = tid; idx < SPB * LRES; idx += NTHREADS) {
    int s = idx >> 8;                // idx / 256
    int l = idx & 255;
    const float* xp = X + ((size_t)(n0 + s) * LRES + l) * QST;
    int b = 0;
#pragma unroll
    for (int j = 0; j < QST; ++j) b = (xp[j] > 0.5f) ? j : b;
    bst[l][s] = b;
  }
  __syncthreads();

  // ---- sequential Gibbs sweep over residues ----
  for (int t = 0; t < LRES; ++t) {
    const int i = order[t];
    const float* Jrow = J + ((size_t)i * QST + a) * (size_t)(LRES * QST);

    // dot: sum over l of J[i,a,l,b_l], replicating Eigen's k-blocked order.
    // k = 21*l + b strictly increases by 1..41 per l, so at most one KC
    // boundary crossing per iteration.
    float tot = 0.0f, part = 0.0f;
    int bnd = KC;
#pragma unroll 8
    for (int l = 0; l < LRES; ++l) {
      int b = bst[l][nl];
      int k = l * QST + b;
      float jv = Jrow[l * QST + b];
      bool  cr = (k >= bnd);
      float tp = tot + part;
      tot  = cr ? tp   : tot;
      part = cr ? 0.0f : part;
      bnd  = cr ? bnd + KC : bnd;
      part += jv;
    }
    tot += part;

    float lo = h[i * QST + a] + tot;       // h_i + dot  (single f32 add)

    // key_t = threefry((0,42),(0,t)); bits = o0^o1 of threefry(key_t,(0,21n+a))
    uint32_t kk0, kk1, o0, o1;
    threefry2x32(0u, 42u, 0u, (uint32_t)t, kk0, kk1);
    threefry2x32(kk0, kk1, 0u, (uint32_t)(n * QST + a), o0, o1);
    float g = gumbel_f32(o0 ^ o1);

    vals[a][nl] = g + beta * lo;           // beta==1.0 -> exact
    __syncthreads();

    if (a == 0) {                          // first-max argmax over 21 cats
      float best = vals[0][nl];
      int bi = 0;
#pragma unroll
      for (int j = 1; j < QST; ++j) {
        float vv = vals[j][nl];
        if (vv > best) { best = vv; bi = j; }
      }
      bst[i][nl] = bi;
    }
    __syncthreads();
  }

  // ---- expand state to one-hot f32 output ----
  const size_t base = (size_t)n0 * LRES * QST;
  for (int idx = tid; idx < SPB * LRES * QST; idx += NTHREADS) {
    int s   = idx / (LRES * QST);
    int rem = idx - s * (LRES * QST);
    int l   = rem / QST;
    int j   = rem - l * QST;
    out[base + idx] = (bst[l][s] == j) ? 1.0f : 0.0f;
  }
}

extern "C" void kernel_launch(void* const* d_in, const int* in_sizes, int n_in,
                              void* d_out, int out_size, void* d_ws, size_t ws_size,
                              hipStream_t stream) {
  const float* X     = (const float*)d_in[0];
  const int*   order = (const int*)  d_in[1];
  const float* h     = (const float*)d_in[2];
  const float* J     = (const float*)d_in[3];
  const float* beta  = (const float*)d_in[4];
  float* out = (float*)d_out;

  dim3 grid(NSEQ / SPB);      // 256 blocks, one per 32 sequences
  dim3 block(SPB, QST);       // 32 x 21 = 672 threads
  hipLaunchKernelGGL(gibbs_sweep, grid, block, 0, stream, X, order, h, J, beta, out);
}